// Round 1
// baseline (750.194 us; speedup 1.0000x reference)
//
#include <hip/hip_runtime.h>
#include <stdint.h>

#define FEAT 512
#define HID  256
#define TILE 64
#define G1   768   // fused_main grid = number of partials

typedef __attribute__((ext_vector_type(8))) short   short8;
typedef __attribute__((ext_vector_type(4))) float   floatx4;

__device__ inline unsigned short f2bf(float x){
  union { float f; uint32_t u; } v; v.f = x;
  uint32_t u = v.u;
  u += 0x7FFFu + ((u >> 16) & 1u);      // round-to-nearest-even
  return (unsigned short)(u >> 16);
}
__device__ inline float bf2f(unsigned short h){
  union { uint32_t u; float f; } v; v.u = ((uint32_t)h) << 16;
  return v.f;
}
__device__ inline float sigm_f(float x){ return 1.f/(1.f + __expf(-x)); }
__device__ inline float tanh_f(float x){ return 2.f/(1.f + __expf(-2.f*x)) - 1.f; }

// ---------------------------------------------------------------------------
// prep: W[K][256] fp32 row-major -> bf16 swizzled to MFMA B-fragment order:
// dst[((kb*16+nt)*64+lane)*8+j] = W[kb*32+(lane>>4)*8+j][nt*16+(lane&15)]
// ---------------------------------------------------------------------------
__global__ void prep_weights(const float* __restrict__ W1, const float* __restrict__ Wa,
                             const float* __restrict__ Wb,
                             unsigned short* __restrict__ W1bf,
                             unsigned short* __restrict__ Wabf,
                             unsigned short* __restrict__ Wbbf){
  int t = blockIdx.x*256 + threadIdx.x;
  const float* src; unsigned short* dst; int g;
  if      (t < 16384){ src = W1; dst = W1bf; g = t; }          // 16 kb * 16 nt * 64
  else if (t < 24576){ src = Wa; dst = Wabf; g = t - 16384; }  // 8 kb
  else if (t < 32768){ src = Wb; dst = Wbbf; g = t - 24576; }  // 8 kb
  else return;
  int lane = g & 63, nt = (g >> 6) & 15, kb = g >> 10;
  int col  = nt*16 + (lane & 15);
  int row0 = kb*32 + (lane >> 4)*8;
  unsigned short* d = dst + (size_t)g*8;
  const float*    s = src + (size_t)row0*HID + col;
  #pragma unroll
  for (int j = 0; j < 8; ++j) d[j] = f2bf(s[(size_t)j*HID]);
}

// ---------------------------------------------------------------------------
// fused_main: per 64-token tile: h=relu(x@W1+b1); a=tanh(h@Wa+ba);
// b=sigm(h@Wb+bb); s=(a*b)@Wc+bc; online softmax accumulate (m,l,g[256]).
// Each wave owns a 16-token strip (MFMA M=16). Writes s to s_buf and a
// per-workgroup partial {m,l,g[256]}.
// ---------------------------------------------------------------------------
__global__ __launch_bounds__(256, 3) void fused_main(
    const float* __restrict__ x,
    const float* __restrict__ b1, const float* __restrict__ ba,
    const float* __restrict__ bb, const float* __restrict__ Wc,
    const float* __restrict__ bc,
    const unsigned short* __restrict__ W1bf,
    const unsigned short* __restrict__ Wabf,
    const unsigned short* __restrict__ Wbbf,
    float* __restrict__ s_buf, float* __restrict__ partials, int ntiles)
{
  __shared__ alignas(16) unsigned short Hs[64][264];  // 64 tokens x 256 h (+8 pad)
  __shared__ alignas(16) unsigned short Ws[8192];     // 16 KB weight staging
  __shared__ float pbuf[4][16];

  const int tid  = threadIdx.x;
  const int wave = tid >> 6, lane = tid & 63;
  const int quad = lane >> 4, l15 = lane & 15;

  float m_run = -INFINITY, l_run = 0.f;
  float g0 = 0.f, g1 = 0.f, g2 = 0.f, g3 = 0.f;   // cols 4*lane .. 4*lane+3
  const float bcv = bc[0];

  for (int t = blockIdx.x; t < ntiles; t += gridDim.x){
    const int tokw = t*TILE + wave*16;

    // ---------------- GEMM1: h = relu(x @ W1 + b1), K=512 ----------------
    floatx4 acc[16];
    #pragma unroll
    for (int nt = 0; nt < 16; ++nt){
      float bv = b1[nt*16 + l15];
      floatx4 tmp = {bv, bv, bv, bv};
      acc[nt] = tmp;
    }
    const float* xrow = x + (size_t)(tokw + l15)*FEAT + quad*8;
    #pragma unroll 1
    for (int kb = 0; kb < 16; ++kb){
      __syncthreads();
      { const short8* srcv = (const short8*)(W1bf + (size_t)kb*8192);
        short8* dstv = (short8*)Ws;
        #pragma unroll
        for (int c = 0; c < 4; ++c) dstv[tid + 256*c] = srcv[tid + 256*c]; }
      __syncthreads();
      const float* xp = xrow + kb*32;
      float4 xa = *(const float4*)xp;
      float4 xb = *(const float4*)(xp + 4);
      union { short8 v; unsigned short u[8]; } af;
      af.u[0]=f2bf(xa.x); af.u[1]=f2bf(xa.y); af.u[2]=f2bf(xa.z); af.u[3]=f2bf(xa.w);
      af.u[4]=f2bf(xb.x); af.u[5]=f2bf(xb.y); af.u[6]=f2bf(xb.z); af.u[7]=f2bf(xb.w);
      #pragma unroll
      for (int nt = 0; nt < 16; ++nt){
        short8 bfv = *(const short8*)&Ws[nt*512 + lane*8];
        acc[nt] = __builtin_amdgcn_mfma_f32_16x16x32_bf16(af.v, bfv, acc[nt], 0, 0, 0);
      }
    }
    // epilogue: relu, store bf16 h into own strip of Hs (same-wave use only)
    #pragma unroll
    for (int nt = 0; nt < 16; ++nt){
      #pragma unroll
      for (int r = 0; r < 4; ++r){
        float hv = fmaxf(acc[nt][r], 0.f);
        Hs[wave*16 + quad*4 + r][nt*16 + l15] = f2bf(hv);
      }
    }

    // ---- GEMM2: a=tanh(h@Wa+ba), b=sigm(h@Wb+bb), s=(a*b)@Wc+bc, K=256 ----
    float sp0 = 0.f, sp1 = 0.f, sp2 = 0.f, sp3 = 0.f;
    #pragma unroll 1
    for (int nh = 0; nh < 2; ++nh){        // N-halves to cap register use
      floatx4 aacc[8], bacc[8];
      #pragma unroll
      for (int nt = 0; nt < 8; ++nt){
        int col = (nh*8 + nt)*16 + l15;
        float av = ba[col], bv = bb[col];
        floatx4 ta = {av, av, av, av}; aacc[nt] = ta;
        floatx4 tb = {bv, bv, bv, bv}; bacc[nt] = tb;
      }
      #pragma unroll 1
      for (int kb = 0; kb < 8; ++kb){
        __syncthreads();
        { const short8* sA = (const short8*)(Wabf + (size_t)(kb*16 + nh*8)*512);
          const short8* sB = (const short8*)(Wbbf + (size_t)(kb*16 + nh*8)*512);
          short8* dstv = (short8*)Ws;
          dstv[tid]       = sA[tid];
          dstv[tid + 256] = sA[tid + 256];
          dstv[tid + 512] = sB[tid];
          dstv[tid + 768] = sB[tid + 256]; }
        __syncthreads();
        short8 af = *(const short8*)&Hs[wave*16 + l15][kb*32 + quad*8];
        #pragma unroll
        for (int nt = 0; nt < 8; ++nt){
          short8 bA = *(const short8*)&Ws[nt*512 + lane*8];
          short8 bB = *(const short8*)&Ws[4096 + nt*512 + lane*8];
          aacc[nt] = __builtin_amdgcn_mfma_f32_16x16x32_bf16(af, bA, aacc[nt], 0, 0, 0);
          bacc[nt] = __builtin_amdgcn_mfma_f32_16x16x32_bf16(af, bB, bacc[nt], 0, 0, 0);
        }
      }
      #pragma unroll
      for (int nt = 0; nt < 8; ++nt){
        int col = (nh*8 + nt)*16 + l15;
        float wcv = Wc[col];
        sp0 += tanh_f(aacc[nt][0]) * sigm_f(bacc[nt][0]) * wcv;
        sp1 += tanh_f(aacc[nt][1]) * sigm_f(bacc[nt][1]) * wcv;
        sp2 += tanh_f(aacc[nt][2]) * sigm_f(bacc[nt][2]) * wcv;
        sp3 += tanh_f(aacc[nt][3]) * sigm_f(bacc[nt][3]) * wcv;
      }
    }
    // reduce s across the 16 lanes of each l15-group (rows = quad*4+r)
    #pragma unroll
    for (int mk = 1; mk < 16; mk <<= 1){
      sp0 += __shfl_xor(sp0, mk, 64);
      sp1 += __shfl_xor(sp1, mk, 64);
      sp2 += __shfl_xor(sp2, mk, 64);
      sp3 += __shfl_xor(sp3, mk, 64);
    }
    float s0 = sp0 + bcv, s1 = sp1 + bcv, s2 = sp2 + bcv, s3 = sp3 + bcv;
    if (l15 == 0){
      float* sb = s_buf + tokw + quad*4;
      sb[0] = s0; sb[1] = s1; sb[2] = s2; sb[3] = s3;
    }
    // online softmax update (per wave)
    float tmax = fmaxf(fmaxf(s0, s1), fmaxf(s2, s3));
    tmax = fmaxf(tmax, __shfl_xor(tmax, 16, 64));
    tmax = fmaxf(tmax, __shfl_xor(tmax, 32, 64));
    float m_new = fmaxf(m_run, tmax);
    float alpha = __expf(m_run - m_new);       // exp(-inf)=0 on first tile
    float p0 = __expf(s0 - m_new), p1 = __expf(s1 - m_new);
    float p2 = __expf(s2 - m_new), p3 = __expf(s3 - m_new);
    float psum = p0 + p1 + p2 + p3;
    psum += __shfl_xor(psum, 16, 64);
    psum += __shfl_xor(psum, 32, 64);          // sum over the 16 rows
    l_run = l_run*alpha + psum;
    m_run = m_new;
    if (l15 == 0){
      pbuf[wave][quad*4+0] = p0; pbuf[wave][quad*4+1] = p1;
      pbuf[wave][quad*4+2] = p2; pbuf[wave][quad*4+3] = p3;
    }
    g0 *= alpha; g1 *= alpha; g2 *= alpha; g3 *= alpha;
    #pragma unroll
    for (int rw = 0; rw < 16; ++rw){
      float pr = pbuf[wave][rw];
      const unsigned short* hp = &Hs[wave*16 + rw][lane*4];
      g0 += pr*bf2f(hp[0]); g1 += pr*bf2f(hp[1]);
      g2 += pr*bf2f(hp[2]); g3 += pr*bf2f(hp[3]);
    }
  }

  // ---- combine 4 waves -> per-workgroup partial {M, L, g[256]} ----
  __syncthreads();
  float* fred = (float*)Ws;                    // reuse staging LDS (4096 floats)
  if (lane == 0) fred[wave] = m_run;
  __syncthreads();
  float M = fmaxf(fmaxf(fred[0], fred[1]), fmaxf(fred[2], fred[3]));
  float sc = (m_run == -INFINITY) ? 0.f : __expf(m_run - M);
  if (lane == 0) fred[4 + wave] = l_run * sc;
  fred[8 + wave*256 + lane*4 + 0] = g0*sc;
  fred[8 + wave*256 + lane*4 + 1] = g1*sc;
  fred[8 + wave*256 + lane*4 + 2] = g2*sc;
  fred[8 + wave*256 + lane*4 + 3] = g3*sc;
  __syncthreads();
  float gsum = fred[8 + 0*256 + tid] + fred[8 + 1*256 + tid]
             + fred[8 + 2*256 + tid] + fred[8 + 3*256 + tid];
  float* P = partials + (size_t)blockIdx.x*258;
  if (tid == 0){ P[0] = M; P[1] = fred[4] + fred[5] + fred[6] + fred[7]; }
  P[2 + tid] = gsum;
}

// ---------------------------------------------------------------------------
// reduce_heads: combine G1 partials -> M, L, global_feat; then hr/cls/reg
// heads in exact fp32. Single workgroup (tiny work).
// ---------------------------------------------------------------------------
__global__ void reduce_heads(const float* __restrict__ partials,
    const float* __restrict__ Wr,   const float* __restrict__ br,
    const float* __restrict__ Wcls, const float* __restrict__ bcls,
    const float* __restrict__ Wreg, const float* __restrict__ breg,
    float* __restrict__ out, float* __restrict__ ML, int ntok)
{
  __shared__ float red[256];
  __shared__ float scw[G1];
  __shared__ float gf[256];
  __shared__ float hr[256];
  int t = threadIdx.x;

  float lm = -INFINITY;
  for (int i = t; i < G1; i += 256) lm = fmaxf(lm, partials[(size_t)i*258]);
  red[t] = lm; __syncthreads();
  for (int s = 128; s > 0; s >>= 1){ if (t < s) red[t] = fmaxf(red[t], red[t+s]); __syncthreads(); }
  float M = red[0];
  __syncthreads();

  float ll = 0.f;
  for (int i = t; i < G1; i += 256){
    float w = __expf(partials[(size_t)i*258] - M);
    scw[i] = w;
    ll += partials[(size_t)i*258 + 1] * w;
  }
  red[t] = ll; __syncthreads();
  for (int s = 128; s > 0; s >>= 1){ if (t < s) red[t] += red[t+s]; __syncthreads(); }
  float L = red[0];

  float g = 0.f;
  for (int i = 0; i < G1; ++i) g += partials[(size_t)i*258 + 2 + t] * scw[i];
  float gfv = g / L;
  gf[t] = gfv;
  out[ntok + t] = gfv;
  if (t == 0){ ML[0] = M; ML[1] = 1.f / L; }
  __syncthreads();

  float h = br[t];
  for (int c = 0; c < 256; ++c) h += gf[c] * Wr[c*256 + t];
  h = fmaxf(h, 0.f);
  hr[t] = h; __syncthreads();

  if (t < 33){
    float v = bcls[t];
    for (int j = 0; j < 256; ++j) v += hr[j] * Wcls[j*33 + t];
    out[ntok + 256 + t] = v;
  }
  if (t < 55){
    float v = breg[t];
    for (int j = 0; j < 256; ++j) v += hr[j] * Wreg[j*55 + t];
    out[ntok + 289 + t] = v;
  }
}

// ---------------------------------------------------------------------------
__global__ void finalize_A(const float* __restrict__ s_buf, const float* __restrict__ ML,
                           float* __restrict__ out, int ntok){
  int i = blockIdx.x*256 + threadIdx.x;
  if (i < ntok) out[i] = __expf(s_buf[i] - ML[0]) * ML[1];
}

// ---------------------------------------------------------------------------
extern "C" void kernel_launch(void* const* d_in, const int* in_sizes, int n_in,
                              void* d_out, int out_size, void* d_ws, size_t ws_size,
                              hipStream_t stream){
  (void)n_in; (void)out_size; (void)ws_size;
  const float* x    = (const float*)d_in[0];
  const float* W1   = (const float*)d_in[1];
  const float* b1   = (const float*)d_in[2];
  const float* Wa   = (const float*)d_in[3];
  const float* ba   = (const float*)d_in[4];
  const float* Wb   = (const float*)d_in[5];
  const float* bb   = (const float*)d_in[6];
  const float* Wc   = (const float*)d_in[7];
  const float* bc   = (const float*)d_in[8];
  const float* Wr   = (const float*)d_in[9];
  const float* br   = (const float*)d_in[10];
  const float* Wcls = (const float*)d_in[11];
  const float* bcls = (const float*)d_in[12];
  const float* Wreg = (const float*)d_in[13];
  const float* breg = (const float*)d_in[14];
  float* out = (float*)d_out;

  const int ntok   = in_sizes[0] / FEAT;   // 200000
  const int ntiles = ntok / TILE;          // 3125 (exact)

  char* ws = (char*)d_ws;
  float* s_buf = (float*)ws;
  size_t off = (size_t)ntok * 4;                               // 800000
  float* partials = (float*)(ws + off); off += (size_t)G1*258*4; // +792576
  float* ML = (float*)(ws + off); off += 16;
  unsigned short* W1bf = (unsigned short*)(ws + off); off += (size_t)FEAT*HID*2;
  unsigned short* Wabf = (unsigned short*)(ws + off); off += (size_t)HID*HID*2;
  unsigned short* Wbbf = (unsigned short*)(ws + off); off += (size_t)HID*HID*2;
  // total ws use ~2.07 MB

  prep_weights<<<128, 256, 0, stream>>>(W1, Wa, Wb, W1bf, Wabf, Wbbf);
  fused_main<<<G1, 256, 0, stream>>>(x, b1, ba, bb, Wc, bc, W1bf, Wabf, Wbbf,
                                     s_buf, partials, ntiles);
  reduce_heads<<<1, 256, 0, stream>>>(partials, Wr, br, Wcls, bcls, Wreg, breg,
                                      out, ML, ntok);
  finalize_A<<<(ntok + 255)/256, 256, 0, stream>>>(s_buf, ML, out, ntok);
}